// Round 15
// baseline (4637.081 us; speedup 1.0000x reference)
//
#include <hip/hip_runtime.h>

#define BDIM 64
#define TDIM 1024
#define DDIM 256
#define HDIM 512
#define RING 8

typedef unsigned short ushort_t;
typedef unsigned int uint32;
typedef unsigned long long ull;
typedef __attribute__((ext_vector_type(8))) short short8;
typedef __attribute__((ext_vector_type(4))) float f32x4;

__device__ __forceinline__ ushort_t f2bf(float f) {
  union { float f; uint32 u; } v; v.f = f;
  uint32 u = v.u;
  return (ushort_t)((u + 0x7fffu + ((u >> 16) & 1u)) >> 16);
}

__device__ __forceinline__ short8 pack8(float4 a, float4 b) {
  short8 s;
  s[0] = (short)f2bf(a.x); s[1] = (short)f2bf(a.y);
  s[2] = (short)f2bf(a.z); s[3] = (short)f2bf(a.w);
  s[4] = (short)f2bf(b.x); s[5] = (short)f2bf(b.y);
  s[6] = (short)f2bf(b.z); s[7] = (short)f2bf(b.w);
  return s;
}

__device__ __forceinline__ ull pack4bf(f32x4 v) {
  return (ull)f2bf(v[0]) | ((ull)f2bf(v[1]) << 16)
       | ((ull)f2bf(v[2]) << 32) | ((ull)f2bf(v[3]) << 48);
}

__device__ __forceinline__ float sigm(float x) { return 1.0f / (1.0f + __expf(-x)); }
__device__ __forceinline__ float tanh_fast(float x) { return 1.0f - 2.0f / (__expf(2.0f * x) + 1.0f); }

__device__ __forceinline__ uint32 ld_sc1(uint32* p) {
  return __hip_atomic_load(p, __ATOMIC_RELAXED, __HIP_MEMORY_SCOPE_AGENT);
}
__device__ __forceinline__ void st_sc1(uint32* p, uint32 v) {
  __hip_atomic_store(p, v, __ATOMIC_RELAXED, __HIP_MEMORY_SCOPE_AGENT);
}
__device__ __forceinline__ void st_sc1_u64(ull* p, ull v) {
  __hip_atomic_store(p, v, __ATOMIC_RELAXED, __HIP_MEMORY_SCOPE_AGENT);
}
__device__ __forceinline__ ull ld_sc1_u64(const ull* p) {
  return __hip_atomic_load((ull*)p, __ATOMIC_RELAXED, __HIP_MEMORY_SCOPE_AGENT);
}

__device__ __forceinline__ void wave_poll_sc1(uint32* fl, uint32 tgt) {
  int it = 0;
  for (;;) {
    uint32 v = ld_sc1(fl);
    if (__all((int)(v >= tgt))) break;
    __builtin_amdgcn_s_sleep(1);
    if (++it > 120000) break;   // bounded: wrong beats hang
  }
  asm volatile("" ::: "memory");
}

// ---- fragment-major LDS layout (conflict-free MFMA reads, r10/r14-proven) ----
__device__ __forceinline__ int frag_off(int row, int kf, int lg) {   // ushort units
  return kf * 512 + (((lg * 16 + row) ^ (kf & 7)) << 3);
}

// ---- r15 staging: 8-row tile (1024 ull), 4 ull/thread, conflict-free b64 writes ----
// element(lane s,h,wvq; q): e2=s&1, kf=(q>>1)*8|((s>>1)&7), lg=h, row=wvq*2+(q&1).
// Within each 16-lane quarter (fixed q): bank8 = ((lg*16+row)^kf012)*2+e2 covers 16
// distinct slots -> conflict-free. Global src L=row*128+kf*8+lg*2+e2: per-wave
// contiguous 512B window per q -> coalescing preserved.
__device__ __forceinline__ void ds_stage(ushort_t* dst, int tid, const ull* v) {
  const int s = tid & 15, h = (tid >> 4) & 3, wvq = tid >> 6;
#pragma unroll
  for (int q = 0; q < 4; ++q) {
    const int row = wvq * 2 + (q & 1);
    const int kf  = ((q >> 1) << 3) | ((s >> 1) & 7);
    *(ull*)&dst[frag_off(row, kf, h) + (s & 1) * 4] = v[q];
  }
}

__device__ __forceinline__ void load_sc1_4(const ull* src, int tid, ull* v) {
  const int s = tid & 15, h = (tid >> 4) & 3, wvq = tid >> 6;
#pragma unroll
  for (int q = 0; q < 4; ++q) {
    const int row = wvq * 2 + (q & 1);
    const int kf  = ((q >> 1) << 3) | ((s >> 1) & 7);
    v[q] = ld_sc1_u64(src + row * 128 + kf * 8 + h * 2 + (s & 1));
  }
}

__global__ void __launch_bounds__(256, 2)
lstm_fused(const float* __restrict__ x,
           const float* __restrict__ w_ih0, const float* __restrict__ w_hh0,
           const float* __restrict__ b0,
           const float* __restrict__ w_ih1, const float* __restrict__ w_hh1,
           const float* __restrict__ b1,
           float* __restrict__ out,
           uint32* cnt0F, uint32* cnt1F, uint32* consF,
           ushort_t* ring, ushort_t* h1buf)
{
  const int b     = (int)blockIdx.x;                 // 0..511
  const int chain = (b + (b >> 8)) & 15;             // bijective; pairs (b, b+256) onto
  const int layer = chain >> 3;                      // different chains per CU
  const int bt    = chain & 7;                       // 0..7 (8 batch rows each)
  const int ct    = (b >> 4) & 31;                   // 0..31
  const int tid   = (int)threadIdx.x;
  const int wv    = tid >> 6;
  const int lane  = tid & 63;
  const int lr    = lane & 15;
  const int lg    = lane >> 4;

  __shared__ __align__(16) ushort_t Is[16 * 512];   // fragment-major (rows 8-15 unused)
  __shared__ __align__(16) ushort_t Hs[16 * 512];
  __shared__ float gates[4][16][16];

  const int NI  = layer ? 16 : 8;
  const int Din = layer ? HDIM : DDIM;
  const float* wih = layer ? w_ih1 : w_ih0;
  const float* whh = layer ? w_hh1 : w_hh0;
  const float* bb  = layer ? b1 : b0;
  const int grow = wv * HDIM + ct * 16 + lr;

  short8 wf[32];
#pragma unroll
  for (int kf = 0; kf < 32; ++kf) wf[kf] = (short8)((short)0);
#pragma unroll
  for (int kf = 0; kf < 32; ++kf) {
    if (kf < NI + 16) {
      const float* src;
      if (kf < NI) src = wih + (size_t)grow * Din + (size_t)kf * 32 + lg * 8;
      else         src = whh + (size_t)grow * HDIM + (size_t)(kf - NI) * 32 + lg * 8;
      float4 a = *(const float4*)(src);
      float4 bq = *(const float4*)(src + 4);
      wf[kf] = pack8(a, bq);
    }
  }
  const float bias = bb[grow];

  const ull* ring_u  = (const ull*)ring;     // [8 slots][8 bt][8 rows][128 ull]
  const ull* h1buf_u = (const ull*)h1buf;    // [2 parity][8 bt][8 rows][128 ull]

  float c4[4] = {0.f, 0.f, 0.f, 0.f};       // wave0 lanes 0-31: cell states
  float4 xpa, xpb;                           // layer0: x[t] prefetch (8 floats)
  const int xrow = tid >> 5;                 // 0..7
  const int xcb  = tid & 31;                 // col block: 8 f32 each

  if (layer == 0) {
    const float4* xv = (const float4*)(x + (size_t)(bt * 8 + xrow) * (TDIM * DDIM) + xcb * 8);
    xpa = xv[0]; xpb = xv[1];
  }

  for (int t = 0; t < TDIM; ++t) {
    // ---- P1: polls (one wave per flag set, throttled — r14 structure) ----
    if (layer == 0) {
      if (wv == 0) {
        if (t > 0) wave_poll_sc1(cnt0F + bt * 32 + (lane & 31), (uint32)t);
      } else if (wv == 1) {
        if (t >= RING) wave_poll_sc1(consF + bt * 32 + (lane & 31), (uint32)(t - RING + 1));
      }
    } else {
      if (wv == 0) {
        if (t > 0) wave_poll_sc1(cnt1F + bt * 32 + (lane & 31), (uint32)t);
      } else if (wv == 1) {
        wave_poll_sc1(cnt0F + bt * 32 + (lane & 31), (uint32)(t + 1));   // y0[t] ready
      }
    }
    __syncthreads();

    // ---- P2/P3: stage inputs ----
    if (layer == 0) {
      {  // x[t]: one 16B chunk per thread (row xrow, cols xcb*8..+8)
        const int c0 = xcb * 8;
        *(short8*)&Is[frag_off(xrow, c0 >> 5, (c0 >> 3) & 3)] = pack8(xpa, xpb);
      }
      if (t > 0) {
        ull hv[4];
        load_sc1_4(ring_u + (size_t)((t - 1) & (RING - 1)) * 8192 + (size_t)bt * 1024, tid, hv);
        ds_stage(Hs, tid, hv);
      }
    } else {
      ull rv[4], hv[4];
      load_sc1_4(ring_u + (size_t)(t & (RING - 1)) * 8192 + (size_t)bt * 1024, tid, rv);
      if (t > 0)
        load_sc1_4(h1buf_u + (size_t)((t - 1) & 1) * 8192 + (size_t)bt * 1024, tid, hv);
      ds_stage(Is, tid, rv);
      if (t > 0) ds_stage(Hs, tid, hv);
    }
    __syncthreads();
    if (layer == 1 && tid == 0)
      st_sc1(consF + bt * 32 + ct, (uint32)(t + 1));   // ring slot consumed

    // ---- P5: MFMA (conflict-free fragment reads; C rows 8-15 garbage, ignored) ----
    f32x4 acc0 = {0.f, 0.f, 0.f, 0.f}, acc1 = {0.f, 0.f, 0.f, 0.f};
#pragma unroll
    for (int kf = 0; kf < 16; ++kf) {
      if (kf < NI) {
        const short8 af = *(const short8*)&Is[frag_off(lr, kf, lg)];
        if (kf & 1) acc1 = __builtin_amdgcn_mfma_f32_16x16x32_bf16(af, wf[kf], acc1, 0, 0, 0);
        else        acc0 = __builtin_amdgcn_mfma_f32_16x16x32_bf16(af, wf[kf], acc0, 0, 0, 0);
      }
    }
    if (t > 0) {
#pragma unroll
      for (int kf = 0; kf < 16; ++kf) {
        const short8 af = *(const short8*)&Hs[frag_off(lr, kf, lg)];
        if (kf & 1) acc1 = __builtin_amdgcn_mfma_f32_16x16x32_bf16(af, wf[NI + kf], acc1, 0, 0, 0);
        else        acc0 = __builtin_amdgcn_mfma_f32_16x16x32_bf16(af, wf[NI + kf], acc0, 0, 0, 0);
      }
    }
#pragma unroll
    for (int i = 0; i < 4; ++i) {
      float v = acc0[i] + acc1[i] + bias;
      float a = (wv < 3) ? sigm(v) : tanh_fast(v);
      gates[wv][lg * 4 + i][lr] = a;
    }
    __syncthreads();

    // ---- P6/P7: pointwise (wave0 lanes 0-31) + publish; others prefetch x ----
    if (layer == 0 && wv != 0 && t + 1 < TDIM) {
      const float4* xv = (const float4*)(x + (size_t)(bt * 8 + xrow) * (TDIM * DDIM)
                                           + (size_t)(t + 1) * DDIM + xcb * 8);
      xpa = xv[0]; xpb = xv[1];
    }
    if (wv == 0) {
      const int r  = lane >> 2;      // 0..15, valid rows 0..7
      const int cg = lane & 3;
      f32x4 nh4, nc4;
      ull hv = 0;
      if (lane < 32) {
        f32x4 gi = *(const f32x4*)&gates[0][r][cg * 4];
        f32x4 gf = *(const f32x4*)&gates[1][r][cg * 4];
        f32x4 go = *(const f32x4*)&gates[2][r][cg * 4];
        f32x4 gg = *(const f32x4*)&gates[3][r][cg * 4];
#pragma unroll
        for (int k = 0; k < 4; ++k) {
          float nc = gf[k] * c4[k] + gi[k] * gg[k];
          float nh = go[k] * tanh_fast(nc);     // h uses UNCLIPPED c
          nc = fminf(fmaxf(nc, -50.f), 50.f);
          nh = fminf(fmaxf(nh, -50.f), 50.f);
          c4[k] = nc; nh4[k] = nh; nc4[k] = nc;
        }
        hv = pack4bf(nh4);
        ull* dst;
        if (layer == 0)
          dst = (ull*)(ring_u + (size_t)(t & (RING - 1)) * 8192
                       + (size_t)bt * 1024 + r * 128 + ct * 4 + cg);
        else
          dst = (ull*)(h1buf_u + (size_t)(t & 1) * 8192
                       + (size_t)bt * 1024 + r * 128 + ct * 4 + cg);
        st_sc1_u64(dst, hv);
      }
      asm volatile("s_waitcnt vmcnt(0)" ::: "memory");
      if (lane == 0) st_sc1((layer == 0 ? cnt0F : cnt1F) + bt * 32 + ct, (uint32)(t + 1));
      if (lane < 32) {
        if (layer == 1)
          *(f32x4*)&out[(size_t)(bt * 8 + r) * (TDIM * HDIM) + (size_t)t * HDIM + ct * 16 + cg * 4] = nh4;
        if (t == TDIM - 1) {
          const size_t OH = (size_t)BDIM * TDIM * HDIM;
          const size_t OC = OH + 2 * (size_t)BDIM * HDIM;
          *(f32x4*)&out[OH + (size_t)layer * BDIM * HDIM + (size_t)(bt * 8 + r) * HDIM + ct * 16 + cg * 4] = nh4;
          *(f32x4*)&out[OC + (size_t)layer * BDIM * HDIM + (size_t)(bt * 8 + r) * HDIM + ct * 16 + cg * 4] = nc4;
        }
      }
      if (layer == 0 && t + 1 < TDIM) {
        const float4* xv = (const float4*)(x + (size_t)(bt * 8 + xrow) * (TDIM * DDIM)
                                             + (size_t)(t + 1) * DDIM + xcb * 8);
        xpa = xv[0]; xpb = xv[1];
      }
    }
  }
}

extern "C" void kernel_launch(void* const* d_in, const int* in_sizes, int n_in,
                              void* d_out, int out_size, void* d_ws, size_t ws_size,
                              hipStream_t stream) {
  (void)in_sizes; (void)n_in; (void)out_size; (void)ws_size;
  const float* x     = (const float*)d_in[0];
  const float* w_ih0 = (const float*)d_in[1];
  const float* w_hh0 = (const float*)d_in[2];
  const float* b0    = (const float*)d_in[3];
  const float* w_ih1 = (const float*)d_in[4];
  const float* w_hh1 = (const float*)d_in[5];
  const float* b1    = (const float*)d_in[6];
  float* out = (float*)d_out;

  char* ws = (char*)d_ws;
  uint32* cnt0F = (uint32*)(ws + 0);       // [8][32]
  uint32* cnt1F = (uint32*)(ws + 1024);    // [8][32]
  uint32* consF = (uint32*)(ws + 2048);    // [8][32]
  ushort_t* ring  = (ushort_t*)(ws + 8192);                 // [8][8][8][512] bf16 (512KB)
  ushort_t* h1buf = (ushort_t*)(ws + 8192 + 524288);        // [2][8][8][512] bf16 (128KB)

  hipMemsetAsync(ws, 0, 4096, stream);
  lstm_fused<<<dim3(512), dim3(256), 0, stream>>>(
      x, w_ih0, w_hh0, b0, w_ih1, w_hh1, b1, out,
      cnt0F, cnt1F, consF, ring, h1buf);
}

// Round 16
// 4047.717 us; speedup vs baseline: 1.1456x; 1.1456x over previous
//
#include <hip/hip_runtime.h>

#define BDIM 64
#define TDIM 1024
#define DDIM 256
#define HDIM 512
#define RING 8

typedef unsigned short ushort_t;
typedef unsigned int uint32;
typedef unsigned long long ull;
typedef __attribute__((ext_vector_type(8))) short short8;
typedef __attribute__((ext_vector_type(4))) float f32x4;

__device__ __forceinline__ ushort_t f2bf(float f) {
  union { float f; uint32 u; } v; v.f = f;
  uint32 u = v.u;
  return (ushort_t)((u + 0x7fffu + ((u >> 16) & 1u)) >> 16);
}

__device__ __forceinline__ short8 pack8(float4 a, float4 b) {
  short8 s;
  s[0] = (short)f2bf(a.x); s[1] = (short)f2bf(a.y);
  s[2] = (short)f2bf(a.z); s[3] = (short)f2bf(a.w);
  s[4] = (short)f2bf(b.x); s[5] = (short)f2bf(b.y);
  s[6] = (short)f2bf(b.z); s[7] = (short)f2bf(b.w);
  return s;
}

__device__ __forceinline__ uint32 ld_sc1(uint32* p) {
  return __hip_atomic_load(p, __ATOMIC_RELAXED, __HIP_MEMORY_SCOPE_AGENT);
}
__device__ __forceinline__ void st_sc1(uint32* p, uint32 v) {
  __hip_atomic_store(p, v, __ATOMIC_RELAXED, __HIP_MEMORY_SCOPE_AGENT);
}
__device__ __forceinline__ void st_sc1_u64(ull* p, ull v) {
  __hip_atomic_store(p, v, __ATOMIC_RELAXED, __HIP_MEMORY_SCOPE_AGENT);
}
__device__ __forceinline__ ull ld_sc1_u64(const ull* p) {
  return __hip_atomic_load((ull*)p, __ATOMIC_RELAXED, __HIP_MEMORY_SCOPE_AGENT);
}

__device__ __forceinline__ void wave_poll_sc1(uint32* fl, uint32 tgt) {
  int it = 0;
  for (;;) {
    uint32 v = ld_sc1(fl);
    if (__all((int)(v >= tgt))) break;
    __builtin_amdgcn_s_sleep(1);
    if (++it > 60000) break;   // bounded: wrong beats hang
  }
  asm volatile("" ::: "memory");
}

// ---- fragment-major LDS layout (conflict-free MFMA reads, r10/r14-proven) ----
__device__ __forceinline__ int frag_off(int row, int kf, int lg) {   // ushort units
  return kf * 512 + (((lg * 16 + row) ^ (kf & 7)) << 3);
}

// ---- blocked global h layout: ull idx = (ct*4 + wv)*16 + row  (2048 ull/chain) ----
// Producer wave wv of block ct stores rows 0..15 of its 4 cols as 16 consecutive
// ull = 128B contiguous. Consumer decodes g -> (ct2,wv2,row) -> chunk coords.
// Staging g = q*256 + tid: per 16-lane quarter ct2/wv2 fixed, row spans 0..15 ->
// bank start = ((row^kf)&7)*4 + e2*2: 8 values x2 lanes, b64 spans 2 banks -> 2-way max.
__device__ __forceinline__ void stage_blocked(ushort_t* dst, int tid, const ull* v) {
#pragma unroll
  for (int q = 0; q < 8; ++q) {
    const int g   = q * 256 + tid;
    const int ct2 = g >> 6, wv2 = (g >> 4) & 3, row = g & 15;
    const int kf  = ct2 >> 1;
    const int lg  = ((ct2 & 1) << 1) | (wv2 >> 1);
    const int e2  = wv2 & 1;
    *(ull*)&dst[frag_off(row, kf, lg) + e2 * 4] = v[q];
  }
}
__device__ __forceinline__ void load_blocked_8(const ull* src, int tid, ull* v) {
#pragma unroll
  for (int q = 0; q < 8; ++q) v[q] = ld_sc1_u64(src + q * 256 + tid);
}

__global__ void __launch_bounds__(256, 1)
lstm_fused(const float* __restrict__ x,
           const float* __restrict__ w_ih0, const float* __restrict__ w_hh0,
           const float* __restrict__ b0,
           const float* __restrict__ w_ih1, const float* __restrict__ w_hh1,
           const float* __restrict__ b1,
           float* __restrict__ out,
           uint32* cnt0F, uint32* cnt1F, uint32* consF,
           ushort_t* ring, ushort_t* h1buf)
{
  const int b     = (int)blockIdx.x;
  const int g     = b & 7;
  const int layer = g >> 2;
  const int bt    = g & 3;
  const int ct    = b >> 3;               // 0..31
  const int tid   = (int)threadIdx.x;
  const int wv    = tid >> 6;
  const int lane  = tid & 63;
  const int n     = lane & 15;            // B/C column within wave tile
  const int rg    = lane >> 4;            // k-chunk (B) / row-group (C)
  const int gsel  = n >> 2;               // gate: 0=i 1=f 2=o 3=g
  const int cgl   = n & 3;                // h-col within wave's 4

  __shared__ __align__(16) ushort_t Is[16 * 512];   // fragment-major
  __shared__ __align__(16) ushort_t Hs[16 * 512];   // fragment-major
  __shared__ __align__(8)  ushort_t htmp[4][16][4]; // per-wave bf16 transpose slab
  __shared__ __align__(16) float htmpF[4][16][4];   // per-wave f32 slab (out / finals)
  __shared__ __align__(16) float htmpC[4][16][4];   // per-wave f32 c-state slab (finals)

  const int NI  = layer ? 16 : 8;
  const int Din = layer ? HDIM : DDIM;
  const float* wih = layer ? w_ih1 : w_ih0;
  const float* whh = layer ? w_hh1 : w_hh0;
  const float* bb  = layer ? b1 : b0;
  // gate-major: this lane's B-column n -> gate gsel, h-col ct*16 + wv*4 + cgl
  const int grow = gsel * HDIM + ct * 16 + wv * 4 + cgl;

  short8 wf[32];
#pragma unroll
  for (int kf = 0; kf < 32; ++kf) wf[kf] = (short8)((short)0);
#pragma unroll
  for (int kf = 0; kf < 32; ++kf) {
    if (kf < NI + 16) {
      const float* src;
      if (kf < NI) src = wih + (size_t)grow * Din + (size_t)kf * 32 + rg * 8;
      else         src = whh + (size_t)grow * HDIM + (size_t)(kf - NI) * 32 + rg * 8;
      float4 a = *(const float4*)(src);
      float4 bq = *(const float4*)(src + 4);
      wf[kf] = pack8(a, bq);
    }
  }
  const float bias = bb[grow];
  const bool isg = (gsel == 3);

  const ull* ring_u  = (const ull*)ring;    // [8 slot][4 bt][2048 blocked]
  const ull* h1buf_u = (const ull*)h1buf;   // [2 par][4 bt][2048 blocked]

  float c4[4] = {0.f, 0.f, 0.f, 0.f};      // lanes n<4: 4 rows x 1 col cell state
  float4 xp0, xp1, xp2, xp3;
  const int xr = tid >> 4;
  const int xcb = tid & 15;

  if (layer == 0) {
    const float4* xv = (const float4*)(x + (size_t)(bt * 16 + xr) * (TDIM * DDIM) + xcb * 16);
    xp0 = xv[0]; xp1 = xv[1]; xp2 = xv[2]; xp3 = xv[3];
  }

  for (int t = 0; t < TDIM; ++t) {
    // ---- P1: polls (one wave per flag set, throttled — r14 structure) ----
    if (layer == 0) {
      if (wv == 0) {
        if (t > 0) wave_poll_sc1(cnt0F + bt * 32 + (lane & 31), (uint32)t);
      } else if (wv == 1) {
        if (t >= RING) wave_poll_sc1(consF + bt * 32 + (lane & 31), (uint32)(t - RING + 1));
      }
    } else {
      if (wv == 0) {
        if (t > 0) wave_poll_sc1(cnt1F + bt * 32 + (lane & 31), (uint32)t);
      } else if (wv == 1) {
        wave_poll_sc1(cnt0F + bt * 32 + (lane & 31), (uint32)(t + 1));   // ring[t] ready
      }
    }
    __syncthreads();   // B0

    // ---- P2/P3: loads + stage ----
    if (layer == 0) {
      {  // x[t] from prefetch regs -> full chunks
        const int c0 = xcb * 16;
        *(short8*)&Is[frag_off(xr, c0 >> 5, (c0 >> 3) & 3)] = pack8(xp0, xp1);
        const int c1 = c0 + 8;
        *(short8*)&Is[frag_off(xr, c1 >> 5, (c1 >> 3) & 3)] = pack8(xp2, xp3);
      }
      if (t > 0) {
        ull hv[8];
        load_blocked_8(ring_u + (size_t)((t - 1) & (RING - 1)) * 8192 + (size_t)bt * 2048, tid, hv);
        stage_blocked(Hs, tid, hv);
      }
    } else {
      ull rv[8], hv[8];
      load_blocked_8(ring_u + (size_t)(t & (RING - 1)) * 8192 + (size_t)bt * 2048, tid, rv);
      if (t > 0)
        load_blocked_8(h1buf_u + (size_t)((t - 1) & 1) * 8192 + (size_t)bt * 2048, tid, hv);
      stage_blocked(Is, tid, rv);
      if (t > 0) stage_blocked(Hs, tid, hv);
    }
    __syncthreads();   // B1
    if (layer == 1 && tid == 0)
      st_sc1(consF + bt * 32 + ct, (uint32)(t + 1));   // ring slot consumed

    // ---- P5: MFMA (gate-major; conflict-free fragment reads) ----
    f32x4 acc0 = {0.f, 0.f, 0.f, 0.f}, acc1 = {0.f, 0.f, 0.f, 0.f};
#pragma unroll
    for (int kf = 0; kf < 16; ++kf) {
      if (kf < NI) {
        const short8 af = *(const short8*)&Is[frag_off(n, kf, rg)];
        if (kf & 1) acc1 = __builtin_amdgcn_mfma_f32_16x16x32_bf16(af, wf[kf], acc1, 0, 0, 0);
        else        acc0 = __builtin_amdgcn_mfma_f32_16x16x32_bf16(af, wf[kf], acc0, 0, 0, 0);
      }
    }
    if (t > 0) {
#pragma unroll
      for (int kf = 0; kf < 16; ++kf) {
        const short8 af = *(const short8*)&Hs[frag_off(n, kf, rg)];
        if (kf & 1) acc1 = __builtin_amdgcn_mfma_f32_16x16x32_bf16(af, wf[NI + kf], acc1, 0, 0, 0);
        else        acc0 = __builtin_amdgcn_mfma_f32_16x16x32_bf16(af, wf[NI + kf], acc0, 0, 0, 0);
      }
    }

    // ---- P6: activation + shfl gate exchange + pointwise (all waves) ----
    float nh4[4], nc4[4];
#pragma unroll
    for (int i = 0; i < 4; ++i) {
      float v = acc0[i] + acc1[i] + bias;
      float e = __expf(isg ? 2.f * v : -v);
      float inv = 1.f / (1.f + e);
      float act = isg ? (1.f - 2.f * inv) : inv;   // tanh for g, sigmoid else
      float fo  = __shfl_xor(act, 4, 64);
      float oo  = __shfl_xor(act, 8, 64);
      float go_ = __shfl_xor(act, 12, 64);
      float nc = fo * c4[i] + act * go_;           // valid on gsel==0 lanes
      float e2 = __expf(2.f * nc);
      float th = 1.f - 2.f / (e2 + 1.f);
      float nh = oo * th;                          // h uses UNCLIPPED c
      nc = fminf(fmaxf(nc, -50.f), 50.f);
      nh = fminf(fmaxf(nh, -50.f), 50.f);
      c4[i] = nc; nh4[i] = nh; nc4[i] = nc;
    }

    // ---- P7a: intra-wave micro-slab transpose (no barrier: same-wave LDS) ----
    if (n < 4) {
#pragma unroll
      for (int i = 0; i < 4; ++i) {
        htmp[wv][rg * 4 + i][cgl] = f2bf(nh4[i]);
        if (layer == 1) htmpF[wv][rg * 4 + i][cgl] = nh4[i];
      }
      if (t == TDIM - 1) {
#pragma unroll
        for (int i = 0; i < 4; ++i) {
          htmpF[wv][rg * 4 + i][cgl] = nh4[i];
          htmpC[wv][rg * 4 + i][cgl] = nc4[i];
        }
      }
    }
    asm volatile("s_waitcnt lgkmcnt(0)" ::: "memory");
    __builtin_amdgcn_sched_barrier(0);

    // ---- P7b: blocked coalesced publish (lanes 0..15 of EACH wave: 128B run) ----
    if (lane < 16) {
      const ull hrow = *(const ull*)&htmp[wv][lane][0];   // row=lane, wave's 4 cols
      const size_t bidx = (size_t)(ct * 4 + wv) * 16 + lane;
      if (layer == 0) {
        st_sc1_u64((ull*)ring_u + (size_t)(t & (RING - 1)) * 8192 + (size_t)bt * 2048 + bidx, hrow);
      } else {
        st_sc1_u64((ull*)h1buf_u + (size_t)(t & 1) * 8192 + (size_t)bt * 2048 + bidx, hrow);
        f32x4 nhf = *(const f32x4*)&htmpF[wv][lane][0];
        *(f32x4*)&out[(size_t)(bt * 16 + lane) * (TDIM * HDIM) + (size_t)t * HDIM
                      + ct * 16 + wv * 4] = nhf;
      }
      if (t == TDIM - 1) {
        const size_t OH = (size_t)BDIM * TDIM * HDIM;
        const size_t OC = OH + 2 * (size_t)BDIM * HDIM;
        f32x4 nhf = *(const f32x4*)&htmpF[wv][lane][0];
        f32x4 ncf = *(const f32x4*)&htmpC[wv][lane][0];
        *(f32x4*)&out[OH + (size_t)layer * BDIM * HDIM + (size_t)(bt * 16 + lane) * HDIM
                      + ct * 16 + wv * 4] = nhf;
        *(f32x4*)&out[OC + (size_t)layer * BDIM * HDIM + (size_t)(bt * 16 + lane) * HDIM
                      + ct * 16 + wv * 4] = ncf;
      }
    }
    asm volatile("s_waitcnt vmcnt(0)" ::: "memory");   // per-wave: its stores acked
    __syncthreads();   // B2: all waves' publishes certified
    if (tid == 0) st_sc1((layer == 0 ? cnt0F : cnt1F) + bt * 32 + ct, (uint32)(t + 1));

    // ---- P8: x prefetch for t+1 (layer0) ----
    if (layer == 0 && t + 1 < TDIM) {
      const float4* xv = (const float4*)(x + (size_t)(bt * 16 + xr) * (TDIM * DDIM)
                                           + (size_t)(t + 1) * DDIM + xcb * 16);
      xp0 = xv[0]; xp1 = xv[1]; xp2 = xv[2]; xp3 = xv[3];
    }
  }
}

extern "C" void kernel_launch(void* const* d_in, const int* in_sizes, int n_in,
                              void* d_out, int out_size, void* d_ws, size_t ws_size,
                              hipStream_t stream) {
  (void)in_sizes; (void)n_in; (void)out_size; (void)ws_size;
  const float* x     = (const float*)d_in[0];
  const float* w_ih0 = (const float*)d_in[1];
  const float* w_hh0 = (const float*)d_in[2];
  const float* b0    = (const float*)d_in[3];
  const float* w_ih1 = (const float*)d_in[4];
  const float* w_hh1 = (const float*)d_in[5];
  const float* b1    = (const float*)d_in[6];
  float* out = (float*)d_out;

  char* ws = (char*)d_ws;
  uint32* cnt0F = (uint32*)(ws + 0);       // [4][32]
  uint32* cnt1F = (uint32*)(ws + 512);     // [4][32]
  uint32* consF = (uint32*)(ws + 1024);    // [4][32]
  ushort_t* ring  = (ushort_t*)(ws + 8192);                 // [8][4][2048 ull] blocked (512KB)
  ushort_t* h1buf = (ushort_t*)(ws + 8192 + 524288);        // [2][4][2048 ull] blocked (128KB)

  hipMemsetAsync(ws, 0, 4096, stream);
  lstm_fused<<<dim3(256), dim3(256), 0, stream>>>(
      x, w_ih0, w_hh0, b0, w_ih1, w_hh1, b1, out,
      cnt0F, cnt1F, consF, ring, h1buf);
}